// Round 9
// baseline (853.302 us; speedup 1.0000x reference)
//
#include <hip/hip_runtime.h>
#include <math.h>

#define M_CENTERS 256
#define D_DIM     512
#define B_BATCH   131072
#define RADIUS    32.0f
#define TAU_F     0.01f
#define EPS_F     1e-6f

#define DMARGIN 2.0e-2f   // d-space ambiguity margin (covers ~7 sigma of bf16 dot noise)
#define REF_BLOCKS 1024
#define NCHUNK 16         // K chunks of 32
#define DSL 16            // dim slices (32 dims each)
#define RCH 16            // row chunks (8192 rows each)

typedef __attribute__((ext_vector_type(8))) short bf16x8;
typedef __attribute__((ext_vector_type(16))) float f32x16;

// packed bf16 convert: lo16 = bf16(a), hi16 = bf16(b)  (v_cvt_pk_bf16_f32, RTNE)
__device__ __forceinline__ unsigned cvt_pk_bf16(float a, float b) {
    unsigned r;
    asm("v_cvt_pk_bf16_f32 %0, %1, %2" : "=v"(r) : "v"(a), "v"(b));
    return r;
}

// ---------------- prep: scale/shift for whitening ----------------
__global__ void prep_ss_kernel(const float* __restrict__ mean, const float* __restrict__ var,
                               float* __restrict__ scale, float* __restrict__ shift) {
    int d = blockIdx.x * 256 + threadIdx.x;
    if (d < D_DIM) {
        float s = 1.0f / sqrtf(var[d] + EPS_F);
        scale[d] = s;
        shift[d] = -mean[d] * s;
    }
}

// ---------------- prep: pack centers bf16(hi) image (granule-major) + center norms ----
// image: chunk kc (0..15) of K=32, 16384 B each: granule g (0..3, = k-slice of 8)
//        x col (0..255) x 16 B:  byte = kc*16384 + g*4096 + col*16
__global__ void prep_cb_kernel(const float* __restrict__ centers, unsigned char* __restrict__ img,
                               float* __restrict__ cn) {
    int c = blockIdx.x;          // 0..255
    int l = threadIdx.x;         // 0..63
    int kc = l >> 2, kq = l & 3;
    const float* cp = centers + (size_t)c * D_DIM + kc * 32 + kq * 8;
    float4 a = *reinterpret_cast<const float4*>(cp);
    float4 b = *reinterpret_cast<const float4*>(cp + 4);
    float s = a.x*a.x + a.y*a.y + a.z*a.z + a.w*a.w + b.x*b.x + b.y*b.y + b.z*b.z + b.w*b.w;
    #pragma unroll
    for (int off = 32; off >= 1; off >>= 1) s += __shfl_xor(s, off, 64);
    if (l == 0) cn[c] = s;

    unsigned h0 = cvt_pk_bf16(a.x, a.y);
    unsigned h1 = cvt_pk_bf16(a.z, a.w);
    unsigned h2 = cvt_pk_bf16(b.x, b.y);
    unsigned h3 = cvt_pk_bf16(b.z, b.w);
    *reinterpret_cast<uint4*>(img + (size_t)kc * 16384 + (size_t)kq * 4096 + (size_t)c * 16) =
        make_uint4(h0, h1, h2, h3);
}

// ---------------- main: MFMA bf16 dists, counted-vmcnt pipeline, depth-2 z prefetch ----
__global__ __launch_bounds__(256, 4)
void dist_mfma_kernel(const float* __restrict__ z,
                      const unsigned char* __restrict__ cb_img,
                      const float* __restrict__ scale, const float* __restrict__ shift,
                      const float* __restrict__ cn,
                      float* __restrict__ out_dists, float* __restrict__ out_idxf,
                      float* __restrict__ out_masks, int* __restrict__ ws_idx,
                      int* __restrict__ counts,
                      int* __restrict__ amb_count, int* __restrict__ amb_rows) {
    __shared__ union {
        // A: 4 granules x 64 rows x 16B = 4096;  B: 4 granules x 256 cols x 16B = 16384
        struct { unsigned char A[2][4096]; unsigned char B[2][16384]; } p;  // 40960 B
        float bounce[2][16][256];                                           // 32768 B
        struct { float znrow[64]; float rminS[64][2]; int ridxS[64][2];
                 int rcntS[64][2]; float fminS[64]; int lhist[M_CENTERS]; } e;
    } sm;

    const int tid = threadIdx.x;
    const int wv = tid >> 6, lane = tid & 63;
    const int rt = wv >> 1, ch = wv & 1;        // row-tile, col-half
    const int l31 = lane & 31, kg = lane >> 5;
    const int b0 = blockIdx.x * 64;

    const int arow = tid >> 2, akq = tid & 3;   // staging: row 0..63, 8-float k-slice
    const float* zrow = z + (size_t)(b0 + arow) * D_DIM;

    f32x16 acc[4];
    #pragma unroll
    for (int n = 0; n < 4; ++n)
        #pragma unroll
        for (int r = 0; r < 16; ++r) acc[n][r] = 0.0f;
    float zsq = 0.0f;

    float4 zbuf[2][2];            // depth-2 z prefetch sets (static under full unroll)
    float4 scv[2], shv[2];        // scale/shift, depth-1

    auto issue_glds = [&](int kc, int cb) {
        const unsigned char* bsrc = cb_img + (size_t)kc * 16384 + (size_t)wv * 4096;
        unsigned char* bdst = &sm.p.B[cb][wv * 4096];
        #pragma unroll
        for (int r = 0; r < 4; ++r) {
            __builtin_amdgcn_global_load_lds(
                (const __attribute__((address_space(1))) unsigned int*)(bsrc + r * 1024 + (lane << 4)),
                (__attribute__((address_space(3))) unsigned int*)(bdst + r * 1024),
                16, 0, 0);
        }
    };
    auto load_scsh = [&](int kc) {
        const int kf = kc * 32 + akq * 8;
        scv[0] = *reinterpret_cast<const float4*>(scale + kf);
        scv[1] = *reinterpret_cast<const float4*>(scale + kf + 4);
        shv[0] = *reinterpret_cast<const float4*>(shift + kf);
        shv[1] = *reinterpret_cast<const float4*>(shift + kf + 4);
    };
    auto load_z = [&](int kc, int set) {
        const int kf = kc * 32 + akq * 8;
        zbuf[set][0] = *reinterpret_cast<const float4*>(zrow + kf);
        zbuf[set][1] = *reinterpret_cast<const float4*>(zrow + kf + 4);
    };
    auto stage_write = [&](int cb, int set) {
        float w0 = fmaf(zbuf[set][0].x, scv[0].x, shv[0].x);
        float w1 = fmaf(zbuf[set][0].y, scv[0].y, shv[0].y);
        float w2 = fmaf(zbuf[set][0].z, scv[0].z, shv[0].z);
        float w3 = fmaf(zbuf[set][0].w, scv[0].w, shv[0].w);
        float w4 = fmaf(zbuf[set][1].x, scv[1].x, shv[1].x);
        float w5 = fmaf(zbuf[set][1].y, scv[1].y, shv[1].y);
        float w6 = fmaf(zbuf[set][1].z, scv[1].z, shv[1].z);
        float w7 = fmaf(zbuf[set][1].w, scv[1].w, shv[1].w);
        zsq = fmaf(w0, w0, fmaf(w1, w1, fmaf(w2, w2, fmaf(w3, w3, zsq))));
        zsq = fmaf(w4, w4, fmaf(w5, w5, fmaf(w6, w6, fmaf(w7, w7, zsq))));
        uint4 hv = make_uint4(cvt_pk_bf16(w0, w1), cvt_pk_bf16(w2, w3),
                              cvt_pk_bf16(w4, w5), cvt_pk_bf16(w6, w7));
        *reinterpret_cast<uint4*>(&sm.p.A[cb][akq * 1024 + arow * 16]) = hv;
    };
    auto mfma_block = [&](int cb) {
        const unsigned char* Ab = &sm.p.A[cb][0];
        const unsigned char* Bb = &sm.p.B[cb][0];
        const int arow16 = (rt * 32 + l31) * 16;
        bf16x8 a0 = *reinterpret_cast<const bf16x8*>(Ab + (0 * 2 + kg) * 1024 + arow16);
        bf16x8 a1 = *reinterpret_cast<const bf16x8*>(Ab + (1 * 2 + kg) * 1024 + arow16);
        #pragma unroll
        for (int n = 0; n < 4; ++n) {
            const int bcol16 = (ch * 128 + n * 32 + l31) * 16;
            bf16x8 b0 = *reinterpret_cast<const bf16x8*>(Bb + (0 * 2 + kg) * 4096 + bcol16);
            bf16x8 b1 = *reinterpret_cast<const bf16x8*>(Bb + (1 * 2 + kg) * 4096 + bcol16);
            acc[n] = __builtin_amdgcn_mfma_f32_32x32x16_bf16(a0, b0, acc[n], 0, 0, 0);
            acc[n] = __builtin_amdgcn_mfma_f32_32x32x16_bf16(a1, b1, acc[n], 0, 0, 0);
        }
    };
    // barrier with counted vmcnt: keep the 2 newest (z prefetch) in flight.
    // issue order in each iter is glds(4), scsh(4), z(2) => vmcnt(2) retires glds+scsh
    // (vmcnt retires oldest-first, m135), so correctness holds even if spills appear.
    auto pipe_barrier = [&]() {
        asm volatile("s_waitcnt vmcnt(2) lgkmcnt(0)" ::: "memory");
        __builtin_amdgcn_s_barrier();
        asm volatile("" ::: "memory");
        __builtin_amdgcn_sched_barrier(0);
    };

    // ---- prologue: chunk0 staged, z(1) in flight ----
    issue_glds(0, 0);          // vm +4
    load_scsh(0);              // vm +4
    load_z(0, 0);              // vm +2
    load_z(1, 1);              // vm +2 (stays in flight across barrier)
    stage_write(0, 0);         // compiler waits scsh0+z0 (vmcnt(2))
    pipe_barrier();

    // ---- main loop: iter kc computes chunk kc, stages kc+1, prefetches z(kc+2) ----
    #pragma unroll
    for (int kc = 0; kc < NCHUNK - 1; ++kc) {
        const int cur = kc & 1, nxt = cur ^ 1;
        issue_glds(kc + 1, nxt);                                 // 4
        load_scsh(kc + 1);                                       // 4
        load_z((kc + 2 < NCHUNK) ? kc + 2 : NCHUNK - 1, kc & 1); // 2 (dummy on kc=14)
        mfma_block(cur);
        stage_write(nxt, (kc + 1) & 1);
        pipe_barrier();
    }
    mfma_block((NCHUNK - 1) & 1);   // chunk 15 from buffer 1

    // ---- zn finalize (A[0] region quiescent; e region lives there) ----
    zsq += __shfl_xor(zsq, 1, 64);
    zsq += __shfl_xor(zsq, 2, 64);
    if (akq == 0) sm.e.znrow[arow] = zsq;
    sm.e.lhist[tid] = 0;
    __syncthreads();

    float znv[16];
    #pragma unroll
    for (int r = 0; r < 16; ++r) znv[r] = sm.e.znrow[rt * 32 + 4 * kg + (r & 3) + 8 * (r >> 2)];
    float cnv[4];
    #pragma unroll
    for (int n = 0; n < 4; ++n) cnv[n] = cn[ch * 128 + n * 32 + l31];

    #pragma unroll
    for (int n = 0; n < 4; ++n)
        #pragma unroll
        for (int r = 0; r < 16; ++r) {
            float d2 = znv[r] + cnv[n] - 2.0f * acc[n][r];
            acc[n][r] = sqrtf(fmaxf(d2, 0.0f));
        }

    // per-row lexicographic (d, col) argmin
    #pragma unroll
    for (int r = 0; r < 16; ++r) {
        float bd = 3.4e38f; int bi = 0;
        #pragma unroll
        for (int n = 0; n < 4; ++n) {
            float d = acc[n][r];
            int col = ch * 128 + n * 32 + l31;
            if (d < bd) { bd = d; bi = col; }
        }
        #pragma unroll
        for (int off = 1; off <= 16; off <<= 1) {
            float od = __shfl_xor(bd, off, 64);
            int   oi = __shfl_xor(bi, off, 64);
            if (od < bd || (od == bd && oi < bi)) { bd = od; bi = oi; }
        }
        if (l31 == 0) {
            int R = rt * 32 + 4 * kg + (r & 3) + 8 * (r >> 2);
            sm.e.rminS[R][ch] = bd; sm.e.ridxS[R][ch] = bi;
        }
    }
    __syncthreads();
    if (tid < 64) {
        float d0 = sm.e.rminS[tid][0], d1 = sm.e.rminS[tid][1];
        int i0 = sm.e.ridxS[tid][0], i1 = sm.e.ridxS[tid][1];
        float fd = d0; int fi = i0;
        if (d1 < d0 || (d1 == d0 && i1 < i0)) { fd = d1; fi = i1; }
        sm.e.fminS[tid] = fd;
        out_idxf[b0 + tid] = (float)fi;
        ws_idx[b0 + tid] = fi;
        atomicAdd(&sm.e.lhist[fi], 1);          // fused histogram
    }
    __syncthreads();
    // ambiguity count
    #pragma unroll
    for (int r = 0; r < 16; ++r) {
        int R = rt * 32 + 4 * kg + (r & 3) + 8 * (r >> 2);
        float thr = sm.e.fminS[R] + DMARGIN;
        int cnt = 0;
        #pragma unroll
        for (int n = 0; n < 4; ++n) cnt += (acc[n][r] <= thr) ? 1 : 0;
        #pragma unroll
        for (int off = 1; off <= 16; off <<= 1) cnt += __shfl_xor(cnt, off, 64);
        if (l31 == 0) sm.e.rcntS[R][ch] = cnt;
    }
    __syncthreads();
    if (tid < 64) {
        if (sm.e.rcntS[tid][0] + sm.e.rcntS[tid][1] > 1) {
            int p = atomicAdd(amb_count, 1);
            if (p < B_BATCH) amb_rows[p] = b0 + tid;
        }
    }
    if (sm.e.lhist[tid] > 0) atomicAdd(&counts[tid], sm.e.lhist[tid]);

    // ---- bounce dists+masks through LDS for coalesced 1KB-row stores ----
    #pragma unroll
    for (int hp = 0; hp < 2; ++hp) {
        __syncthreads();
        #pragma unroll
        for (int rr = 0; rr < 8; ++rr) {
            const int r = hp * 8 + rr;
            const int Rl = 4 * kg + (r & 3) + 8 * (r >> 2) - hp * 16;   // 0..15
            #pragma unroll
            for (int n = 0; n < 4; ++n)
                sm.bounce[rt][Rl][ch * 128 + n * 32 + l31] = acc[n][r];
        }
        __syncthreads();
        #pragma unroll
        for (int i = 0; i < 8; ++i) {
            const int Rl = ch * 8 + i;
            float4 dq = *reinterpret_cast<const float4*>(&sm.bounce[rt][Rl][lane * 4]);
            const int grow = b0 + rt * 32 + hp * 16 + Rl;
            size_t ob = (size_t)grow * M_CENTERS + lane * 4;
            *reinterpret_cast<float4*>(out_dists + ob) = dq;
            float4 mq = make_float4(dq.x <= RADIUS ? 1.0f : 0.0f, dq.y <= RADIUS ? 1.0f : 0.0f,
                                    dq.z <= RADIUS ? 1.0f : 0.0f, dq.w <= RADIUS ? 1.0f : 0.0f);
            *reinterpret_cast<float4*>(out_masks + ob) = mq;
        }
    }
}

// ---------------- refinement: emulate numpy's fp32 decision pipeline ----------------
// Also patches the fused histogram counts when it changes an assignment.
__global__ __launch_bounds__(64)
void refine_kernel(const float* __restrict__ z, const float* __restrict__ centers,
                   const float* __restrict__ smean, const float* __restrict__ svar,
                   const float* __restrict__ dists,
                   const int* __restrict__ amb_count, const int* __restrict__ amb_rows,
                   float* __restrict__ out_idxf, int* __restrict__ ws_idx,
                   int* __restrict__ counts) {
    const int lane = threadIdx.x;  // 0..63
    int n = *amb_count;
    if (n > B_BATCH) n = B_BATCH;
    for (int e = blockIdx.x; e < n; e += REF_BLOCKS) {
        const int row = amb_rows[e];
        float4 dq = *reinterpret_cast<const float4*>(dists + (size_t)row * M_CENTERS + lane * 4);
        float dl[4] = { dq.x, dq.y, dq.z, dq.w };
        float dmin = fminf(fminf(dl[0], dl[1]), fminf(dl[2], dl[3]));
        #pragma unroll
        for (int off = 32; off >= 1; off >>= 1) dmin = fminf(dmin, __shfl_xor(dmin, off, 64));

        float zwf[8];
        double zn = 0.0;
        {
            float4 za = *reinterpret_cast<const float4*>(z + (size_t)row * D_DIM + lane * 8);
            float4 zb = *reinterpret_cast<const float4*>(z + (size_t)row * D_DIM + lane * 8 + 4);
            float zr[8] = { za.x, za.y, za.z, za.w, zb.x, zb.y, zb.z, zb.w };
            #pragma unroll
            for (int k = 0; k < 8; ++k) {
                int d = lane * 8 + k;
                float w = (zr[k] - smean[d]) / sqrtf(svar[d] + EPS_F);   // pure fp32 ops
                zwf[k] = w;
                zn += (double)w * (double)w;
            }
        }
        #pragma unroll
        for (int off = 32; off >= 1; off >>= 1) zn += __shfl_xor(zn, off, 64);
        const float zn32 = (float)zn;

        float bestd = 3.4e38f;
        int bestj = M_CENTERS;
        #pragma unroll
        for (int q = 0; q < 4; ++q) {
            unsigned long long mask = __ballot(dl[q] <= dmin + DMARGIN);
            while (mask) {
                int b = __ffsll(mask) - 1;
                mask &= mask - 1;
                int j = b * 4 + q;
                float4 ca = *reinterpret_cast<const float4*>(centers + (size_t)j * D_DIM + lane * 8);
                float4 cb = *reinterpret_cast<const float4*>(centers + (size_t)j * D_DIM + lane * 8 + 4);
                float cr[8] = { ca.x, ca.y, ca.z, ca.w, cb.x, cb.y, cb.z, cb.w };
                double dot = 0.0, cnl = 0.0;
                #pragma unroll
                for (int k = 0; k < 8; ++k) {
                    double c = (double)cr[k];
                    dot += (double)zwf[k] * c;
                    cnl += c * c;
                }
                #pragma unroll
                for (int off = 32; off >= 1; off >>= 1) {
                    dot += __shfl_xor(dot, off, 64);
                    cnl += __shfl_xor(cnl, off, 64);
                }
                float cn32  = (float)cnl;
                float dot32 = (float)dot;
                float t1  = zn32 + cn32;
                float d2f = t1 - 2.0f * dot32;
                d2f = fmaxf(d2f, 0.0f);
                float df = sqrtf(d2f);
                if (df < bestd || (df == bestd && j < bestj)) { bestd = df; bestj = j; }
            }
        }
        if (lane == 0) {
            int old = ws_idx[row];
            if (old != bestj) {
                atomicSub(&counts[old], 1);
                atomicAdd(&counts[bestj], 1);
                out_idxf[row] = (float)bestj;
                ws_idx[row]   = bestj;
            }
        }
    }
}

// ---------------- phase B: slab accumulator (coalesced z stream, LDS atomic) ----------
// grid = RCH * DSL blocks; block (rc, ds) accumulates whitened z of rows
// [rc*8192, (rc+1)*8192) for dims [ds*32, ds*32+32) into LDS [256][32].
__global__ __launch_bounds__(256)
void update_slab_kernel(const float* __restrict__ z,
                        const float* __restrict__ scale, const float* __restrict__ shift,
                        const int* __restrict__ ws_idx, float* __restrict__ partial) {
    __shared__ float lsum[M_CENTERS][32];   // 32 KB
    const int ds = blockIdx.x & (DSL - 1);
    const int rc = blockIdx.x >> 4;
    const int tid = threadIdx.x;
    const int lane_d = tid & 31, rgrp = tid >> 5;  // 8 row groups
    const int d0 = ds * 32 + lane_d;

    #pragma unroll
    for (int m = rgrp; m < M_CENTERS; m += 8) lsum[m][lane_d] = 0.0f;
    __syncthreads();

    const float sc = scale[d0], sh = shift[d0];
    const int rows = B_BATCH / RCH;
    const int base = rc * rows;
    for (int r = rgrp; r < rows; r += 32) {
        int row0 = base + r, row1 = row0 + 8, row2 = row0 + 16, row3 = row0 + 24;
        int m0 = ws_idx[row0], m1 = ws_idx[row1], m2 = ws_idx[row2], m3 = ws_idx[row3];
        float v0 = z[(size_t)row0 * D_DIM + d0];
        float v1 = z[(size_t)row1 * D_DIM + d0];
        float v2 = z[(size_t)row2 * D_DIM + d0];
        float v3 = z[(size_t)row3 * D_DIM + d0];
        atomicAdd(&lsum[m0][lane_d], fmaf(v0, sc, sh));
        atomicAdd(&lsum[m1][lane_d], fmaf(v1, sc, sh));
        atomicAdd(&lsum[m2][lane_d], fmaf(v2, sc, sh));
        atomicAdd(&lsum[m3][lane_d], fmaf(v3, sc, sh));
    }
    __syncthreads();
    #pragma unroll
    for (int m = rgrp; m < M_CENTERS; m += 8)
        partial[((size_t)rc * M_CENTERS + m) * D_DIM + d0] = lsum[m][lane_d];
}

// ---------------- phase B: fold partials + EMA ----------------
__global__ __launch_bounds__(128)
void ema_reduce_kernel(const float* __restrict__ centers,
                       const int* __restrict__ counts,
                       const float* __restrict__ partial,
                       float* __restrict__ out_nc) {
    const int m = blockIdx.x;
    const int t = threadIdx.x;
    const int d0 = t * 4;
    const int cnt = counts[m];
    float a0 = 0.0f, a1 = 0.0f, a2 = 0.0f, a3 = 0.0f;
    #pragma unroll
    for (int rc = 0; rc < RCH; ++rc) {
        float4 v = *reinterpret_cast<const float4*>(partial + ((size_t)rc * M_CENTERS + m) * D_DIM + d0);
        a0 += v.x; a1 += v.y; a2 += v.z; a3 += v.w;
    }
    float4 cv = *reinterpret_cast<const float4*>(centers + (size_t)m * D_DIM + d0);
    float4 r = cv;
    if (cnt > 0) {
        float inv = 1.0f / (float)cnt;
        r.x = (1.0f - TAU_F) * cv.x + TAU_F * (a0 * inv);
        r.y = (1.0f - TAU_F) * cv.y + TAU_F * (a1 * inv);
        r.z = (1.0f - TAU_F) * cv.z + TAU_F * (a2 * inv);
        r.w = (1.0f - TAU_F) * cv.w + TAU_F * (a3 * inv);
    }
    *reinterpret_cast<float4*>(out_nc + (size_t)m * D_DIM + d0) = r;
}

extern "C" void kernel_launch(void* const* d_in, const int* in_sizes, int n_in,
                              void* d_out, int out_size, void* d_ws, size_t ws_size,
                              hipStream_t stream) {
    const float* z       = (const float*)d_in[0];
    const float* centers = (const float*)d_in[1];
    const float* smean   = (const float*)d_in[2];
    const float* svar    = (const float*)d_in[3];

    float* out = (float*)d_out;
    float* out_dists = out;                                        // B*M
    float* out_idxf  = out + (size_t)B_BATCH * M_CENTERS;          // B
    float* out_masks = out_idxf + B_BATCH;                         // B*M
    float* out_nc    = out_masks + (size_t)B_BATCH * M_CENTERS;    // M*D

    char* wsp = (char*)d_ws;
    float* scale   = (float*)wsp; wsp += D_DIM * sizeof(float);
    float* shift   = (float*)wsp; wsp += D_DIM * sizeof(float);
    float* cn      = (float*)wsp; wsp += M_CENTERS * sizeof(float);
    int* ws_idx    = (int*)wsp;   wsp += (size_t)B_BATCH * sizeof(int);
    int* counts    = (int*)wsp;   wsp += M_CENTERS * sizeof(int);
    int* amb_count = (int*)wsp;   wsp += 4 * sizeof(int);          // adjacent to counts (one memset)
    int* amb_rows  = (int*)wsp;   wsp += (size_t)B_BATCH * sizeof(int);
    float* partial = (float*)wsp; wsp += (size_t)RCH * M_CENTERS * D_DIM * sizeof(float);
    unsigned char* cb_img = (unsigned char*)wsp; wsp += (size_t)NCHUNK * 16384;

    prep_ss_kernel<<<2, 256, 0, stream>>>(smean, svar, scale, shift);
    prep_cb_kernel<<<M_CENTERS, 64, 0, stream>>>(centers, cb_img, cn);
    hipMemsetAsync(counts, 0, (M_CENTERS + 4) * sizeof(int), stream);  // counts + amb_count
    dist_mfma_kernel<<<B_BATCH / 64, 256, 0, stream>>>(z, cb_img, scale, shift, cn,
                                                       out_dists, out_idxf, out_masks, ws_idx,
                                                       counts, amb_count, amb_rows);
    refine_kernel<<<REF_BLOCKS, 64, 0, stream>>>(z, centers, smean, svar, out_dists,
                                                 amb_count, amb_rows, out_idxf, ws_idx, counts);
    update_slab_kernel<<<RCH * DSL, 256, 0, stream>>>(z, scale, shift, ws_idx, partial);
    ema_reduce_kernel<<<M_CENTERS, 128, 0, stream>>>(centers, counts, partial, out_nc);
}

// Round 10
// 532.647 us; speedup vs baseline: 1.6020x; 1.6020x over previous
//
#include <hip/hip_runtime.h>
#include <math.h>

#define M_CENTERS 256
#define D_DIM     512
#define B_BATCH   131072
#define RADIUS    32.0f
#define TAU_F     0.01f
#define EPS_F     1e-6f

#define DMARGIN 2.0e-2f   // d-space ambiguity margin (covers ~7 sigma of bf16 dot noise)
#define REF_BLOCKS 1024
#define NCHUNK 16         // K chunks of 32
#define DSL 32            // dim slices (16 dims each)
#define RCH 32            // row chunks (4096 rows each)

typedef __attribute__((ext_vector_type(8))) short bf16x8;
typedef __attribute__((ext_vector_type(16))) float f32x16;

// packed bf16 convert: lo16 = bf16(a), hi16 = bf16(b)  (v_cvt_pk_bf16_f32, RTNE)
__device__ __forceinline__ unsigned cvt_pk_bf16(float a, float b) {
    unsigned r;
    asm("v_cvt_pk_bf16_f32 %0, %1, %2" : "=v"(r) : "v"(a), "v"(b));
    return r;
}

// ---------------- prep: scale/shift for whitening ----------------
__global__ void prep_ss_kernel(const float* __restrict__ mean, const float* __restrict__ var,
                               float* __restrict__ scale, float* __restrict__ shift) {
    int d = blockIdx.x * 256 + threadIdx.x;
    if (d < D_DIM) {
        float s = 1.0f / sqrtf(var[d] + EPS_F);
        scale[d] = s;
        shift[d] = -mean[d] * s;
    }
}

// ---------------- prep: pack centers bf16(hi) image (granule-major) + center norms ----
__global__ void prep_cb_kernel(const float* __restrict__ centers, unsigned char* __restrict__ img,
                               float* __restrict__ cn) {
    int c = blockIdx.x;          // 0..255
    int l = threadIdx.x;         // 0..63
    int kc = l >> 2, kq = l & 3;
    const float* cp = centers + (size_t)c * D_DIM + kc * 32 + kq * 8;
    float4 a = *reinterpret_cast<const float4*>(cp);
    float4 b = *reinterpret_cast<const float4*>(cp + 4);
    float s = a.x*a.x + a.y*a.y + a.z*a.z + a.w*a.w + b.x*b.x + b.y*b.y + b.z*b.z + b.w*b.w;
    #pragma unroll
    for (int off = 32; off >= 1; off >>= 1) s += __shfl_xor(s, off, 64);
    if (l == 0) cn[c] = s;

    unsigned h0 = cvt_pk_bf16(a.x, a.y);
    unsigned h1 = cvt_pk_bf16(a.z, a.w);
    unsigned h2 = cvt_pk_bf16(b.x, b.y);
    unsigned h3 = cvt_pk_bf16(b.z, b.w);
    *reinterpret_cast<uint4*>(img + (size_t)kc * 16384 + (size_t)kq * 4096 + (size_t)c * 16) =
        make_uint4(h0, h1, h2, h3);
}

// ---------------- main: MFMA bf16 dists + argmin + masks + ambiguity + histogram ------
// (Round-8 verified version: compiler-scheduled double buffer, __syncthreads only.)
__global__ __launch_bounds__(256, 4)
void dist_mfma_kernel(const float* __restrict__ z,
                      const unsigned char* __restrict__ cb_img,
                      const float* __restrict__ scale, const float* __restrict__ shift,
                      const float* __restrict__ cn,
                      float* __restrict__ out_dists, float* __restrict__ out_idxf,
                      float* __restrict__ out_masks, int* __restrict__ ws_idx,
                      int* __restrict__ counts,
                      int* __restrict__ amb_count, int* __restrict__ amb_rows) {
    __shared__ union {
        struct { unsigned char A[2][4096]; unsigned char B[2][16384]; } p;  // 40960 B
        float bounce[2][16][256];                                           // 32768 B
        struct { float znrow[64]; float rminS[64][2]; int ridxS[64][2];
                 int rcntS[64][2]; float fminS[64]; int lhist[M_CENTERS]; } e;
    } sm;

    const int tid = threadIdx.x;
    const int wv = tid >> 6, lane = tid & 63;
    const int rt = wv >> 1, ch = wv & 1;        // row-tile, col-half
    const int l31 = lane & 31, kg = lane >> 5;
    const int b0 = blockIdx.x * 64;

    const int arow = tid >> 2, akq = tid & 3;   // staging: row 0..63, 8-float k-slice
    const float* zrow = z + (size_t)(b0 + arow) * D_DIM;

    f32x16 acc[4];
    #pragma unroll
    for (int n = 0; n < 4; ++n)
        #pragma unroll
        for (int r = 0; r < 16; ++r) acc[n][r] = 0.0f;
    float zsq = 0.0f;
    float4 zv, zv2, scv, scv2, shv, shv2;

    auto stage_load = [&](int kc, int cb) {
        const unsigned char* bsrc = cb_img + (size_t)kc * 16384 + (size_t)wv * 4096;
        unsigned char* bdst = &sm.p.B[cb][wv * 4096];
        #pragma unroll
        for (int r = 0; r < 4; ++r) {
            __builtin_amdgcn_global_load_lds(
                (const __attribute__((address_space(1))) unsigned int*)(bsrc + r * 1024 + (lane << 4)),
                (__attribute__((address_space(3))) unsigned int*)(bdst + r * 1024),
                16, 0, 0);
        }
        const int kf = kc * 32 + akq * 8;
        zv   = *reinterpret_cast<const float4*>(zrow + kf);
        zv2  = *reinterpret_cast<const float4*>(zrow + kf + 4);
        scv  = *reinterpret_cast<const float4*>(scale + kf);
        scv2 = *reinterpret_cast<const float4*>(scale + kf + 4);
        shv  = *reinterpret_cast<const float4*>(shift + kf);
        shv2 = *reinterpret_cast<const float4*>(shift + kf + 4);
    };
    auto stage_write = [&](int cb) {
        float w0 = fmaf(zv.x,  scv.x,  shv.x);
        float w1 = fmaf(zv.y,  scv.y,  shv.y);
        float w2 = fmaf(zv.z,  scv.z,  shv.z);
        float w3 = fmaf(zv.w,  scv.w,  shv.w);
        float w4 = fmaf(zv2.x, scv2.x, shv2.x);
        float w5 = fmaf(zv2.y, scv2.y, shv2.y);
        float w6 = fmaf(zv2.z, scv2.z, shv2.z);
        float w7 = fmaf(zv2.w, scv2.w, shv2.w);
        zsq = fmaf(w0, w0, fmaf(w1, w1, fmaf(w2, w2, fmaf(w3, w3, zsq))));
        zsq = fmaf(w4, w4, fmaf(w5, w5, fmaf(w6, w6, fmaf(w7, w7, zsq))));
        uint4 hv = make_uint4(cvt_pk_bf16(w0, w1), cvt_pk_bf16(w2, w3),
                              cvt_pk_bf16(w4, w5), cvt_pk_bf16(w6, w7));
        *reinterpret_cast<uint4*>(&sm.p.A[cb][akq * 1024 + arow * 16]) = hv;
    };

    stage_load(0, 0);
    stage_write(0);
    __syncthreads();

    int cc = 0;
    for (int kc = 0; kc < NCHUNK; ++kc) {
        const bool pf = (kc + 1 < NCHUNK);
        if (pf) stage_load(kc + 1, cc ^ 1);     // issue early (glds B + z regs)
        const unsigned char* Ab = &sm.p.A[cc][0];
        const unsigned char* Bb = &sm.p.B[cc][0];
        const int arow16 = (rt * 32 + l31) * 16;
        bf16x8 a0 = *reinterpret_cast<const bf16x8*>(Ab + (0 * 2 + kg) * 1024 + arow16);
        bf16x8 a1 = *reinterpret_cast<const bf16x8*>(Ab + (1 * 2 + kg) * 1024 + arow16);
        #pragma unroll
        for (int n = 0; n < 4; ++n) {
            const int bcol16 = (ch * 128 + n * 32 + l31) * 16;
            bf16x8 b0 = *reinterpret_cast<const bf16x8*>(Bb + (0 * 2 + kg) * 4096 + bcol16);
            bf16x8 b1 = *reinterpret_cast<const bf16x8*>(Bb + (1 * 2 + kg) * 4096 + bcol16);
            acc[n] = __builtin_amdgcn_mfma_f32_32x32x16_bf16(a0, b0, acc[n], 0, 0, 0);
            acc[n] = __builtin_amdgcn_mfma_f32_32x32x16_bf16(a1, b1, acc[n], 0, 0, 0);
        }
        if (pf) stage_write(cc ^ 1);            // write late (z arrived during MFMA)
        __syncthreads();
        cc ^= 1;
    }

    // ---- zn finalize (p region dead; e region begins) ----
    zsq += __shfl_xor(zsq, 1, 64);
    zsq += __shfl_xor(zsq, 2, 64);
    if (akq == 0) sm.e.znrow[arow] = zsq;
    sm.e.lhist[tid] = 0;
    __syncthreads();

    float znv[16];
    #pragma unroll
    for (int r = 0; r < 16; ++r) znv[r] = sm.e.znrow[rt * 32 + 4 * kg + (r & 3) + 8 * (r >> 2)];
    float cnv[4];
    #pragma unroll
    for (int n = 0; n < 4; ++n) cnv[n] = cn[ch * 128 + n * 32 + l31];

    #pragma unroll
    for (int n = 0; n < 4; ++n)
        #pragma unroll
        for (int r = 0; r < 16; ++r) {
            float d2 = znv[r] + cnv[n] - 2.0f * acc[n][r];
            acc[n][r] = sqrtf(fmaxf(d2, 0.0f));
        }

    // per-row lexicographic (d, col) argmin
    #pragma unroll
    for (int r = 0; r < 16; ++r) {
        float bd = 3.4e38f; int bi = 0;
        #pragma unroll
        for (int n = 0; n < 4; ++n) {
            float d = acc[n][r];
            int col = ch * 128 + n * 32 + l31;
            if (d < bd) { bd = d; bi = col; }
        }
        #pragma unroll
        for (int off = 1; off <= 16; off <<= 1) {
            float od = __shfl_xor(bd, off, 64);
            int   oi = __shfl_xor(bi, off, 64);
            if (od < bd || (od == bd && oi < bi)) { bd = od; bi = oi; }
        }
        if (l31 == 0) {
            int R = rt * 32 + 4 * kg + (r & 3) + 8 * (r >> 2);
            sm.e.rminS[R][ch] = bd; sm.e.ridxS[R][ch] = bi;
        }
    }
    __syncthreads();
    if (tid < 64) {
        float d0 = sm.e.rminS[tid][0], d1 = sm.e.rminS[tid][1];
        int i0 = sm.e.ridxS[tid][0], i1 = sm.e.ridxS[tid][1];
        float fd = d0; int fi = i0;
        if (d1 < d0 || (d1 == d0 && i1 < i0)) { fd = d1; fi = i1; }
        sm.e.fminS[tid] = fd;
        out_idxf[b0 + tid] = (float)fi;
        ws_idx[b0 + tid] = fi;
        atomicAdd(&sm.e.lhist[fi], 1);          // fused histogram
    }
    __syncthreads();
    // ambiguity count
    #pragma unroll
    for (int r = 0; r < 16; ++r) {
        int R = rt * 32 + 4 * kg + (r & 3) + 8 * (r >> 2);
        float thr = sm.e.fminS[R] + DMARGIN;
        int cnt = 0;
        #pragma unroll
        for (int n = 0; n < 4; ++n) cnt += (acc[n][r] <= thr) ? 1 : 0;
        #pragma unroll
        for (int off = 1; off <= 16; off <<= 1) cnt += __shfl_xor(cnt, off, 64);
        if (l31 == 0) sm.e.rcntS[R][ch] = cnt;
    }
    __syncthreads();
    if (tid < 64) {
        if (sm.e.rcntS[tid][0] + sm.e.rcntS[tid][1] > 1) {
            int p = atomicAdd(amb_count, 1);
            if (p < B_BATCH) amb_rows[p] = b0 + tid;
        }
    }
    if (sm.e.lhist[tid] > 0) atomicAdd(&counts[tid], sm.e.lhist[tid]);

    // ---- bounce dists+masks through LDS for coalesced 1KB-row stores ----
    #pragma unroll
    for (int hp = 0; hp < 2; ++hp) {
        __syncthreads();
        #pragma unroll
        for (int rr = 0; rr < 8; ++rr) {
            const int r = hp * 8 + rr;
            const int Rl = 4 * kg + (r & 3) + 8 * (r >> 2) - hp * 16;   // 0..15
            #pragma unroll
            for (int n = 0; n < 4; ++n)
                sm.bounce[rt][Rl][ch * 128 + n * 32 + l31] = acc[n][r];
        }
        __syncthreads();
        #pragma unroll
        for (int i = 0; i < 8; ++i) {
            const int Rl = ch * 8 + i;
            float4 dq = *reinterpret_cast<const float4*>(&sm.bounce[rt][Rl][lane * 4]);
            const int grow = b0 + rt * 32 + hp * 16 + Rl;
            size_t ob = (size_t)grow * M_CENTERS + lane * 4;
            *reinterpret_cast<float4*>(out_dists + ob) = dq;
            float4 mq = make_float4(dq.x <= RADIUS ? 1.0f : 0.0f, dq.y <= RADIUS ? 1.0f : 0.0f,
                                    dq.z <= RADIUS ? 1.0f : 0.0f, dq.w <= RADIUS ? 1.0f : 0.0f);
            *reinterpret_cast<float4*>(out_masks + ob) = mq;
        }
    }
}

// ---------------- refinement: emulate numpy's fp32 decision pipeline ----------------
__global__ __launch_bounds__(64)
void refine_kernel(const float* __restrict__ z, const float* __restrict__ centers,
                   const float* __restrict__ smean, const float* __restrict__ svar,
                   const float* __restrict__ dists,
                   const int* __restrict__ amb_count, const int* __restrict__ amb_rows,
                   float* __restrict__ out_idxf, int* __restrict__ ws_idx,
                   int* __restrict__ counts) {
    const int lane = threadIdx.x;  // 0..63
    int n = *amb_count;
    if (n > B_BATCH) n = B_BATCH;
    for (int e = blockIdx.x; e < n; e += REF_BLOCKS) {
        const int row = amb_rows[e];
        float4 dq = *reinterpret_cast<const float4*>(dists + (size_t)row * M_CENTERS + lane * 4);
        float dl[4] = { dq.x, dq.y, dq.z, dq.w };
        float dmin = fminf(fminf(dl[0], dl[1]), fminf(dl[2], dl[3]));
        #pragma unroll
        for (int off = 32; off >= 1; off >>= 1) dmin = fminf(dmin, __shfl_xor(dmin, off, 64));

        float zwf[8];
        double zn = 0.0;
        {
            float4 za = *reinterpret_cast<const float4*>(z + (size_t)row * D_DIM + lane * 8);
            float4 zb = *reinterpret_cast<const float4*>(z + (size_t)row * D_DIM + lane * 8 + 4);
            float zr[8] = { za.x, za.y, za.z, za.w, zb.x, zb.y, zb.z, zb.w };
            #pragma unroll
            for (int k = 0; k < 8; ++k) {
                int d = lane * 8 + k;
                float w = (zr[k] - smean[d]) / sqrtf(svar[d] + EPS_F);   // pure fp32 ops
                zwf[k] = w;
                zn += (double)w * (double)w;
            }
        }
        #pragma unroll
        for (int off = 32; off >= 1; off >>= 1) zn += __shfl_xor(zn, off, 64);
        const float zn32 = (float)zn;

        float bestd = 3.4e38f;
        int bestj = M_CENTERS;
        #pragma unroll
        for (int q = 0; q < 4; ++q) {
            unsigned long long mask = __ballot(dl[q] <= dmin + DMARGIN);
            while (mask) {
                int b = __ffsll(mask) - 1;
                mask &= mask - 1;
                int j = b * 4 + q;
                float4 ca = *reinterpret_cast<const float4*>(centers + (size_t)j * D_DIM + lane * 8);
                float4 cb = *reinterpret_cast<const float4*>(centers + (size_t)j * D_DIM + lane * 8 + 4);
                float cr[8] = { ca.x, ca.y, ca.z, ca.w, cb.x, cb.y, cb.z, cb.w };
                double dot = 0.0, cnl = 0.0;
                #pragma unroll
                for (int k = 0; k < 8; ++k) {
                    double c = (double)cr[k];
                    dot += (double)zwf[k] * c;
                    cnl += c * c;
                }
                #pragma unroll
                for (int off = 32; off >= 1; off >>= 1) {
                    dot += __shfl_xor(dot, off, 64);
                    cnl += __shfl_xor(cnl, off, 64);
                }
                float cn32  = (float)cnl;
                float dot32 = (float)dot;
                float t1  = zn32 + cn32;
                float d2f = t1 - 2.0f * dot32;
                d2f = fmaxf(d2f, 0.0f);
                float df = sqrtf(d2f);
                if (df < bestd || (df == bestd && j < bestj)) { bestd = df; bestj = j; }
            }
        }
        if (lane == 0) {
            int old = ws_idx[row];
            if (old != bestj) {
                atomicSub(&counts[old], 1);
                atomicAdd(&counts[bestj], 1);
                out_idxf[row] = (float)bestj;
                ws_idx[row]   = bestj;
            }
        }
    }
}

// ---------------- phase B: slab accumulator, high occupancy ----------
// grid = RCH * DSL blocks (1024); block (rc, ds) accumulates whitened z of rows
// [rc*4096, (rc+1)*4096) for dims [ds*16, ds*16+16) into LDS [256][16] (16 KB).
__global__ __launch_bounds__(256, 4)
void update_slab_kernel(const float* __restrict__ z,
                        const float* __restrict__ scale, const float* __restrict__ shift,
                        const int* __restrict__ ws_idx, float* __restrict__ partial) {
    __shared__ float lsum[M_CENTERS][16];   // 16 KB
    const int ds = blockIdx.x & (DSL - 1);
    const int rc = blockIdx.x >> 5;
    const int tid = threadIdx.x;
    const int lane_d = tid & 15, rgrp = tid >> 4;  // 16 row groups
    const int d0 = ds * 16 + lane_d;

    #pragma unroll
    for (int m = rgrp; m < M_CENTERS; m += 16) lsum[m][lane_d] = 0.0f;
    __syncthreads();

    const float sc = scale[d0], sh = shift[d0];
    const int rows = B_BATCH / RCH;      // 4096
    const int base = rc * rows;
    for (int r = rgrp; r < rows; r += 128) {
        int rw[8]; int mm[8]; float vv[8];
        #pragma unroll
        for (int j = 0; j < 8; ++j) rw[j] = base + r + j * 16;
        #pragma unroll
        for (int j = 0; j < 8; ++j) mm[j] = ws_idx[rw[j]];
        #pragma unroll
        for (int j = 0; j < 8; ++j) vv[j] = z[(size_t)rw[j] * D_DIM + d0];
        #pragma unroll
        for (int j = 0; j < 8; ++j) atomicAdd(&lsum[mm[j]][lane_d], fmaf(vv[j], sc, sh));
    }
    __syncthreads();
    #pragma unroll
    for (int m = rgrp; m < M_CENTERS; m += 16)
        partial[((size_t)rc * M_CENTERS + m) * D_DIM + d0] = lsum[m][lane_d];
}

// ---------------- phase B: fold partials + EMA ----------------
__global__ __launch_bounds__(128)
void ema_reduce_kernel(const float* __restrict__ centers,
                       const int* __restrict__ counts,
                       const float* __restrict__ partial,
                       float* __restrict__ out_nc) {
    const int m = blockIdx.x;
    const int t = threadIdx.x;
    const int d0 = t * 4;
    const int cnt = counts[m];
    float a0 = 0.0f, a1 = 0.0f, a2 = 0.0f, a3 = 0.0f;
    #pragma unroll
    for (int rc = 0; rc < RCH; ++rc) {
        float4 v = *reinterpret_cast<const float4*>(partial + ((size_t)rc * M_CENTERS + m) * D_DIM + d0);
        a0 += v.x; a1 += v.y; a2 += v.z; a3 += v.w;
    }
    float4 cv = *reinterpret_cast<const float4*>(centers + (size_t)m * D_DIM + d0);
    float4 r = cv;
    if (cnt > 0) {
        float inv = 1.0f / (float)cnt;
        r.x = (1.0f - TAU_F) * cv.x + TAU_F * (a0 * inv);
        r.y = (1.0f - TAU_F) * cv.y + TAU_F * (a1 * inv);
        r.z = (1.0f - TAU_F) * cv.z + TAU_F * (a2 * inv);
        r.w = (1.0f - TAU_F) * cv.w + TAU_F * (a3 * inv);
    }
    *reinterpret_cast<float4*>(out_nc + (size_t)m * D_DIM + d0) = r;
}

extern "C" void kernel_launch(void* const* d_in, const int* in_sizes, int n_in,
                              void* d_out, int out_size, void* d_ws, size_t ws_size,
                              hipStream_t stream) {
    const float* z       = (const float*)d_in[0];
    const float* centers = (const float*)d_in[1];
    const float* smean   = (const float*)d_in[2];
    const float* svar    = (const float*)d_in[3];

    float* out = (float*)d_out;
    float* out_dists = out;                                        // B*M
    float* out_idxf  = out + (size_t)B_BATCH * M_CENTERS;          // B
    float* out_masks = out_idxf + B_BATCH;                         // B*M
    float* out_nc    = out_masks + (size_t)B_BATCH * M_CENTERS;    // M*D

    char* wsp = (char*)d_ws;
    float* scale   = (float*)wsp; wsp += D_DIM * sizeof(float);
    float* shift   = (float*)wsp; wsp += D_DIM * sizeof(float);
    float* cn      = (float*)wsp; wsp += M_CENTERS * sizeof(float);
    int* ws_idx    = (int*)wsp;   wsp += (size_t)B_BATCH * sizeof(int);
    int* counts    = (int*)wsp;   wsp += M_CENTERS * sizeof(int);
    int* amb_count = (int*)wsp;   wsp += 4 * sizeof(int);          // adjacent to counts (one memset)
    int* amb_rows  = (int*)wsp;   wsp += (size_t)B_BATCH * sizeof(int);
    float* partial = (float*)wsp; wsp += (size_t)RCH * M_CENTERS * D_DIM * sizeof(float);
    unsigned char* cb_img = (unsigned char*)wsp; wsp += (size_t)NCHUNK * 16384;

    prep_ss_kernel<<<2, 256, 0, stream>>>(smean, svar, scale, shift);
    prep_cb_kernel<<<M_CENTERS, 64, 0, stream>>>(centers, cb_img, cn);
    hipMemsetAsync(counts, 0, (M_CENTERS + 4) * sizeof(int), stream);  // counts + amb_count
    dist_mfma_kernel<<<B_BATCH / 64, 256, 0, stream>>>(z, cb_img, scale, shift, cn,
                                                       out_dists, out_idxf, out_masks, ws_idx,
                                                       counts, amb_count, amb_rows);
    refine_kernel<<<REF_BLOCKS, 64, 0, stream>>>(z, centers, smean, svar, out_dists,
                                                 amb_count, amb_rows, out_idxf, ws_idx, counts);
    update_slab_kernel<<<RCH * DSL, 256, 0, stream>>>(z, scale, shift, ws_idx, partial);
    ema_reduce_kernel<<<M_CENTERS, 128, 0, stream>>>(centers, counts, partial, out_nc);
}

// Round 11
// 295.348 us; speedup vs baseline: 2.8891x; 1.8035x over previous
//
#include <hip/hip_runtime.h>
#include <math.h>

#define M_CENTERS 256
#define D_DIM     512
#define B_BATCH   131072
#define RADIUS    32.0f
#define TAU_F     0.01f
#define EPS_F     1e-6f

#define DMARGIN 2.0e-2f   // d-space ambiguity margin (covers ~7 sigma of bf16 dot noise)
#define REF_BLOCKS 1024
#define UCHUNKS 32
#define NCHUNK 16         // K chunks of 32
#define SC_ROWS 512

typedef __attribute__((ext_vector_type(8))) short bf16x8;
typedef __attribute__((ext_vector_type(16))) float f32x16;

// packed bf16 convert: lo16 = bf16(a), hi16 = bf16(b)  (v_cvt_pk_bf16_f32, RTNE)
__device__ __forceinline__ unsigned cvt_pk_bf16(float a, float b) {
    unsigned r;
    asm("v_cvt_pk_bf16_f32 %0, %1, %2" : "=v"(r) : "v"(a), "v"(b));
    return r;
}

// ---------------- prep: scale/shift for whitening ----------------
__global__ void prep_ss_kernel(const float* __restrict__ mean, const float* __restrict__ var,
                               float* __restrict__ scale, float* __restrict__ shift) {
    int d = blockIdx.x * 256 + threadIdx.x;
    if (d < D_DIM) {
        float s = 1.0f / sqrtf(var[d] + EPS_F);
        scale[d] = s;
        shift[d] = -mean[d] * s;
    }
}

// ---------------- prep: pack centers bf16(hi) image (granule-major) + center norms ----
__global__ void prep_cb_kernel(const float* __restrict__ centers, unsigned char* __restrict__ img,
                               float* __restrict__ cn) {
    int c = blockIdx.x;          // 0..255
    int l = threadIdx.x;         // 0..63
    int kc = l >> 2, kq = l & 3;
    const float* cp = centers + (size_t)c * D_DIM + kc * 32 + kq * 8;
    float4 a = *reinterpret_cast<const float4*>(cp);
    float4 b = *reinterpret_cast<const float4*>(cp + 4);
    float s = a.x*a.x + a.y*a.y + a.z*a.z + a.w*a.w + b.x*b.x + b.y*b.y + b.z*b.z + b.w*b.w;
    #pragma unroll
    for (int off = 32; off >= 1; off >>= 1) s += __shfl_xor(s, off, 64);
    if (l == 0) cn[c] = s;

    unsigned h0 = cvt_pk_bf16(a.x, a.y);
    unsigned h1 = cvt_pk_bf16(a.z, a.w);
    unsigned h2 = cvt_pk_bf16(b.x, b.y);
    unsigned h3 = cvt_pk_bf16(b.z, b.w);
    *reinterpret_cast<uint4*>(img + (size_t)kc * 16384 + (size_t)kq * 4096 + (size_t)c * 16) =
        make_uint4(h0, h1, h2, h3);
}

// ---------------- main: MFMA bf16 dists + argmin + masks + ambiguity + histogram ------
// (Round-8 verified version: compiler-scheduled double buffer, __syncthreads only.)
__global__ __launch_bounds__(256, 4)
void dist_mfma_kernel(const float* __restrict__ z,
                      const unsigned char* __restrict__ cb_img,
                      const float* __restrict__ scale, const float* __restrict__ shift,
                      const float* __restrict__ cn,
                      float* __restrict__ out_dists, float* __restrict__ out_idxf,
                      float* __restrict__ out_masks, int* __restrict__ ws_idx,
                      int* __restrict__ counts,
                      int* __restrict__ amb_count, int* __restrict__ amb_rows) {
    __shared__ union {
        struct { unsigned char A[2][4096]; unsigned char B[2][16384]; } p;  // 40960 B
        float bounce[2][16][256];                                           // 32768 B
        struct { float znrow[64]; float rminS[64][2]; int ridxS[64][2];
                 int rcntS[64][2]; float fminS[64]; int lhist[M_CENTERS]; } e;
    } sm;

    const int tid = threadIdx.x;
    const int wv = tid >> 6, lane = tid & 63;
    const int rt = wv >> 1, ch = wv & 1;        // row-tile, col-half
    const int l31 = lane & 31, kg = lane >> 5;
    const int b0 = blockIdx.x * 64;

    const int arow = tid >> 2, akq = tid & 3;   // staging: row 0..63, 8-float k-slice
    const float* zrow = z + (size_t)(b0 + arow) * D_DIM;

    f32x16 acc[4];
    #pragma unroll
    for (int n = 0; n < 4; ++n)
        #pragma unroll
        for (int r = 0; r < 16; ++r) acc[n][r] = 0.0f;
    float zsq = 0.0f;
    float4 zv, zv2, scv, scv2, shv, shv2;

    auto stage_load = [&](int kc, int cb) {
        const unsigned char* bsrc = cb_img + (size_t)kc * 16384 + (size_t)wv * 4096;
        unsigned char* bdst = &sm.p.B[cb][wv * 4096];
        #pragma unroll
        for (int r = 0; r < 4; ++r) {
            __builtin_amdgcn_global_load_lds(
                (const __attribute__((address_space(1))) unsigned int*)(bsrc + r * 1024 + (lane << 4)),
                (__attribute__((address_space(3))) unsigned int*)(bdst + r * 1024),
                16, 0, 0);
        }
        const int kf = kc * 32 + akq * 8;
        zv   = *reinterpret_cast<const float4*>(zrow + kf);
        zv2  = *reinterpret_cast<const float4*>(zrow + kf + 4);
        scv  = *reinterpret_cast<const float4*>(scale + kf);
        scv2 = *reinterpret_cast<const float4*>(scale + kf + 4);
        shv  = *reinterpret_cast<const float4*>(shift + kf);
        shv2 = *reinterpret_cast<const float4*>(shift + kf + 4);
    };
    auto stage_write = [&](int cb) {
        float w0 = fmaf(zv.x,  scv.x,  shv.x);
        float w1 = fmaf(zv.y,  scv.y,  shv.y);
        float w2 = fmaf(zv.z,  scv.z,  shv.z);
        float w3 = fmaf(zv.w,  scv.w,  shv.w);
        float w4 = fmaf(zv2.x, scv2.x, shv2.x);
        float w5 = fmaf(zv2.y, scv2.y, shv2.y);
        float w6 = fmaf(zv2.z, scv2.z, shv2.z);
        float w7 = fmaf(zv2.w, scv2.w, shv2.w);
        zsq = fmaf(w0, w0, fmaf(w1, w1, fmaf(w2, w2, fmaf(w3, w3, zsq))));
        zsq = fmaf(w4, w4, fmaf(w5, w5, fmaf(w6, w6, fmaf(w7, w7, zsq))));
        uint4 hv = make_uint4(cvt_pk_bf16(w0, w1), cvt_pk_bf16(w2, w3),
                              cvt_pk_bf16(w4, w5), cvt_pk_bf16(w6, w7));
        *reinterpret_cast<uint4*>(&sm.p.A[cb][akq * 1024 + arow * 16]) = hv;
    };

    stage_load(0, 0);
    stage_write(0);
    __syncthreads();

    int cc = 0;
    for (int kc = 0; kc < NCHUNK; ++kc) {
        const bool pf = (kc + 1 < NCHUNK);
        if (pf) stage_load(kc + 1, cc ^ 1);     // issue early (glds B + z regs)
        const unsigned char* Ab = &sm.p.A[cc][0];
        const unsigned char* Bb = &sm.p.B[cc][0];
        const int arow16 = (rt * 32 + l31) * 16;
        bf16x8 a0 = *reinterpret_cast<const bf16x8*>(Ab + (0 * 2 + kg) * 1024 + arow16);
        bf16x8 a1 = *reinterpret_cast<const bf16x8*>(Ab + (1 * 2 + kg) * 1024 + arow16);
        #pragma unroll
        for (int n = 0; n < 4; ++n) {
            const int bcol16 = (ch * 128 + n * 32 + l31) * 16;
            bf16x8 b0 = *reinterpret_cast<const bf16x8*>(Bb + (0 * 2 + kg) * 4096 + bcol16);
            bf16x8 b1 = *reinterpret_cast<const bf16x8*>(Bb + (1 * 2 + kg) * 4096 + bcol16);
            acc[n] = __builtin_amdgcn_mfma_f32_32x32x16_bf16(a0, b0, acc[n], 0, 0, 0);
            acc[n] = __builtin_amdgcn_mfma_f32_32x32x16_bf16(a1, b1, acc[n], 0, 0, 0);
        }
        if (pf) stage_write(cc ^ 1);            // write late (z arrived during MFMA)
        __syncthreads();
        cc ^= 1;
    }

    // ---- zn finalize (p region dead; e region begins) ----
    zsq += __shfl_xor(zsq, 1, 64);
    zsq += __shfl_xor(zsq, 2, 64);
    if (akq == 0) sm.e.znrow[arow] = zsq;
    sm.e.lhist[tid] = 0;
    __syncthreads();

    float znv[16];
    #pragma unroll
    for (int r = 0; r < 16; ++r) znv[r] = sm.e.znrow[rt * 32 + 4 * kg + (r & 3) + 8 * (r >> 2)];
    float cnv[4];
    #pragma unroll
    for (int n = 0; n < 4; ++n) cnv[n] = cn[ch * 128 + n * 32 + l31];

    #pragma unroll
    for (int n = 0; n < 4; ++n)
        #pragma unroll
        for (int r = 0; r < 16; ++r) {
            float d2 = znv[r] + cnv[n] - 2.0f * acc[n][r];
            acc[n][r] = sqrtf(fmaxf(d2, 0.0f));
        }

    // per-row lexicographic (d, col) argmin
    #pragma unroll
    for (int r = 0; r < 16; ++r) {
        float bd = 3.4e38f; int bi = 0;
        #pragma unroll
        for (int n = 0; n < 4; ++n) {
            float d = acc[n][r];
            int col = ch * 128 + n * 32 + l31;
            if (d < bd) { bd = d; bi = col; }
        }
        #pragma unroll
        for (int off = 1; off <= 16; off <<= 1) {
            float od = __shfl_xor(bd, off, 64);
            int   oi = __shfl_xor(bi, off, 64);
            if (od < bd || (od == bd && oi < bi)) { bd = od; bi = oi; }
        }
        if (l31 == 0) {
            int R = rt * 32 + 4 * kg + (r & 3) + 8 * (r >> 2);
            sm.e.rminS[R][ch] = bd; sm.e.ridxS[R][ch] = bi;
        }
    }
    __syncthreads();
    if (tid < 64) {
        float d0 = sm.e.rminS[tid][0], d1 = sm.e.rminS[tid][1];
        int i0 = sm.e.ridxS[tid][0], i1 = sm.e.ridxS[tid][1];
        float fd = d0; int fi = i0;
        if (d1 < d0 || (d1 == d0 && i1 < i0)) { fd = d1; fi = i1; }
        sm.e.fminS[tid] = fd;
        out_idxf[b0 + tid] = (float)fi;
        ws_idx[b0 + tid] = fi;
        atomicAdd(&sm.e.lhist[fi], 1);          // fused histogram
    }
    __syncthreads();
    // ambiguity count
    #pragma unroll
    for (int r = 0; r < 16; ++r) {
        int R = rt * 32 + 4 * kg + (r & 3) + 8 * (r >> 2);
        float thr = sm.e.fminS[R] + DMARGIN;
        int cnt = 0;
        #pragma unroll
        for (int n = 0; n < 4; ++n) cnt += (acc[n][r] <= thr) ? 1 : 0;
        #pragma unroll
        for (int off = 1; off <= 16; off <<= 1) cnt += __shfl_xor(cnt, off, 64);
        if (l31 == 0) sm.e.rcntS[R][ch] = cnt;
    }
    __syncthreads();
    if (tid < 64) {
        if (sm.e.rcntS[tid][0] + sm.e.rcntS[tid][1] > 1) {
            int p = atomicAdd(amb_count, 1);
            if (p < B_BATCH) amb_rows[p] = b0 + tid;
        }
    }
    if (sm.e.lhist[tid] > 0) atomicAdd(&counts[tid], sm.e.lhist[tid]);

    // ---- bounce dists+masks through LDS for coalesced 1KB-row stores ----
    #pragma unroll
    for (int hp = 0; hp < 2; ++hp) {
        __syncthreads();
        #pragma unroll
        for (int rr = 0; rr < 8; ++rr) {
            const int r = hp * 8 + rr;
            const int Rl = 4 * kg + (r & 3) + 8 * (r >> 2) - hp * 16;   // 0..15
            #pragma unroll
            for (int n = 0; n < 4; ++n)
                sm.bounce[rt][Rl][ch * 128 + n * 32 + l31] = acc[n][r];
        }
        __syncthreads();
        #pragma unroll
        for (int i = 0; i < 8; ++i) {
            const int Rl = ch * 8 + i;
            float4 dq = *reinterpret_cast<const float4*>(&sm.bounce[rt][Rl][lane * 4]);
            const int grow = b0 + rt * 32 + hp * 16 + Rl;
            size_t ob = (size_t)grow * M_CENTERS + lane * 4;
            *reinterpret_cast<float4*>(out_dists + ob) = dq;
            float4 mq = make_float4(dq.x <= RADIUS ? 1.0f : 0.0f, dq.y <= RADIUS ? 1.0f : 0.0f,
                                    dq.z <= RADIUS ? 1.0f : 0.0f, dq.w <= RADIUS ? 1.0f : 0.0f);
            *reinterpret_cast<float4*>(out_masks + ob) = mq;
        }
    }
}

// ---------------- refinement: emulate numpy's fp32 decision pipeline ----------------
__global__ __launch_bounds__(64)
void refine_kernel(const float* __restrict__ z, const float* __restrict__ centers,
                   const float* __restrict__ smean, const float* __restrict__ svar,
                   const float* __restrict__ dists,
                   const int* __restrict__ amb_count, const int* __restrict__ amb_rows,
                   float* __restrict__ out_idxf, int* __restrict__ ws_idx,
                   int* __restrict__ counts) {
    const int lane = threadIdx.x;  // 0..63
    int n = *amb_count;
    if (n > B_BATCH) n = B_BATCH;
    for (int e = blockIdx.x; e < n; e += REF_BLOCKS) {
        const int row = amb_rows[e];
        float4 dq = *reinterpret_cast<const float4*>(dists + (size_t)row * M_CENTERS + lane * 4);
        float dl[4] = { dq.x, dq.y, dq.z, dq.w };
        float dmin = fminf(fminf(dl[0], dl[1]), fminf(dl[2], dl[3]));
        #pragma unroll
        for (int off = 32; off >= 1; off >>= 1) dmin = fminf(dmin, __shfl_xor(dmin, off, 64));

        float zwf[8];
        double zn = 0.0;
        {
            float4 za = *reinterpret_cast<const float4*>(z + (size_t)row * D_DIM + lane * 8);
            float4 zb = *reinterpret_cast<const float4*>(z + (size_t)row * D_DIM + lane * 8 + 4);
            float zr[8] = { za.x, za.y, za.z, za.w, zb.x, zb.y, zb.z, zb.w };
            #pragma unroll
            for (int k = 0; k < 8; ++k) {
                int d = lane * 8 + k;
                float w = (zr[k] - smean[d]) / sqrtf(svar[d] + EPS_F);   // pure fp32 ops
                zwf[k] = w;
                zn += (double)w * (double)w;
            }
        }
        #pragma unroll
        for (int off = 32; off >= 1; off >>= 1) zn += __shfl_xor(zn, off, 64);
        const float zn32 = (float)zn;

        float bestd = 3.4e38f;
        int bestj = M_CENTERS;
        #pragma unroll
        for (int q = 0; q < 4; ++q) {
            unsigned long long mask = __ballot(dl[q] <= dmin + DMARGIN);
            while (mask) {
                int b = __ffsll(mask) - 1;
                mask &= mask - 1;
                int j = b * 4 + q;
                float4 ca = *reinterpret_cast<const float4*>(centers + (size_t)j * D_DIM + lane * 8);
                float4 cb = *reinterpret_cast<const float4*>(centers + (size_t)j * D_DIM + lane * 8 + 4);
                float cr[8] = { ca.x, ca.y, ca.z, ca.w, cb.x, cb.y, cb.z, cb.w };
                double dot = 0.0, cnl = 0.0;
                #pragma unroll
                for (int k = 0; k < 8; ++k) {
                    double c = (double)cr[k];
                    dot += (double)zwf[k] * c;
                    cnl += c * c;
                }
                #pragma unroll
                for (int off = 32; off >= 1; off >>= 1) {
                    dot += __shfl_xor(dot, off, 64);
                    cnl += __shfl_xor(cnl, off, 64);
                }
                float cn32  = (float)cnl;
                float dot32 = (float)dot;
                float t1  = zn32 + cn32;
                float d2f = t1 - 2.0f * dot32;
                d2f = fmaxf(d2f, 0.0f);
                float df = sqrtf(d2f);
                if (df < bestd || (df == bestd && j < bestj)) { bestd = df; bestj = j; }
            }
        }
        if (lane == 0) {
            int old = ws_idx[row];
            if (old != bestj) {
                atomicSub(&counts[old], 1);
                atomicAdd(&counts[bestj], 1);
                out_idxf[row] = (float)bestj;
                ws_idx[row]   = bestj;
            }
        }
    }
}

// ---------------- phase B: prefix scan ----------------
__global__ void scan_kernel(const int* __restrict__ counts, int* __restrict__ offsets,
                            int* __restrict__ cursor) {
    __shared__ int s[M_CENTERS];
    int t = threadIdx.x;
    int c = counts[t];
    s[t] = c;
    __syncthreads();
    for (int off = 1; off < M_CENTERS; off <<= 1) {
        int v = (t >= off) ? s[t - off] : 0;
        __syncthreads();
        s[t] += v;
        __syncthreads();
    }
    int excl = s[t] - c;
    offsets[t] = excl;
    cursor[t]  = excl;
    if (t == M_CENTERS - 1) offsets[M_CENTERS] = s[t];
}

// ---------------- phase B: block-aggregated scatter ----------------
__global__ __launch_bounds__(256)
void scatter2_kernel(const int* __restrict__ idx, int* __restrict__ cursor,
                     int* __restrict__ order) {
    __shared__ int lh[M_CENTERS];
    __shared__ int lb[M_CENTERS];
    const int t = threadIdx.x;
    lh[t] = 0;
    __syncthreads();
    const int base = blockIdx.x * SC_ROWS;
    int m[2], pl[2];
    #pragma unroll
    for (int k = 0; k < 2; ++k) {
        m[k] = idx[base + k * 256 + t];
        pl[k] = atomicAdd(&lh[m[k]], 1);
    }
    __syncthreads();
    int c = lh[t];
    if (c > 0) lb[t] = atomicAdd(&cursor[t], c);
    __syncthreads();
    #pragma unroll
    for (int k = 0; k < 2; ++k)
        order[lb[m[k]] + pl[k]] = base + k * 256 + t;
}

// ---------------- phase B: chunked partial sums (float4, deep TLP) ----------------
__global__ __launch_bounds__(128)
void update_partial_kernel(const float* __restrict__ z,
                           const float* __restrict__ scale, const float* __restrict__ shift,
                           const int* __restrict__ offsets, const int* __restrict__ order,
                           float* __restrict__ partial) {
    const int m = blockIdx.x / UCHUNKS;
    const int c = blockIdx.x % UCHUNKS;
    const int t = threadIdx.x;
    const int d0 = t * 4;
    const int start = offsets[m], end = offsets[m + 1];
    const int len = end - start;
    const int cs = (len + UCHUNKS - 1) / UCHUNKS;
    const int s0 = start + c * cs;
    int s1 = s0 + cs; if (s1 > end) s1 = end;

    const float4 sc = *reinterpret_cast<const float4*>(scale + d0);
    const float4 sh = *reinterpret_cast<const float4*>(shift + d0);
    float a0 = 0.0f, a1 = 0.0f, a2 = 0.0f, a3 = 0.0f;
    int i = s0;
    for (; i + 4 <= s1; i += 4) {
        int b0 = order[i], b1 = order[i + 1], b2 = order[i + 2], b3 = order[i + 3];
        float4 v0 = *reinterpret_cast<const float4*>(z + (size_t)b0 * D_DIM + d0);
        float4 v1 = *reinterpret_cast<const float4*>(z + (size_t)b1 * D_DIM + d0);
        float4 v2 = *reinterpret_cast<const float4*>(z + (size_t)b2 * D_DIM + d0);
        float4 v3 = *reinterpret_cast<const float4*>(z + (size_t)b3 * D_DIM + d0);
        a0 += fmaf(v0.x, sc.x, sh.x); a1 += fmaf(v0.y, sc.y, sh.y);
        a2 += fmaf(v0.z, sc.z, sh.z); a3 += fmaf(v0.w, sc.w, sh.w);
        a0 += fmaf(v1.x, sc.x, sh.x); a1 += fmaf(v1.y, sc.y, sh.y);
        a2 += fmaf(v1.z, sc.z, sh.z); a3 += fmaf(v1.w, sc.w, sh.w);
        a0 += fmaf(v2.x, sc.x, sh.x); a1 += fmaf(v2.y, sc.y, sh.y);
        a2 += fmaf(v2.z, sc.z, sh.z); a3 += fmaf(v2.w, sc.w, sh.w);
        a0 += fmaf(v3.x, sc.x, sh.x); a1 += fmaf(v3.y, sc.y, sh.y);
        a2 += fmaf(v3.z, sc.z, sh.z); a3 += fmaf(v3.w, sc.w, sh.w);
    }
    for (; i < s1; ++i) {
        int b = order[i];
        float4 v = *reinterpret_cast<const float4*>(z + (size_t)b * D_DIM + d0);
        a0 += fmaf(v.x, sc.x, sh.x); a1 += fmaf(v.y, sc.y, sh.y);
        a2 += fmaf(v.z, sc.z, sh.z); a3 += fmaf(v.w, sc.w, sh.w);
    }
    *reinterpret_cast<float4*>(partial + ((size_t)blockIdx.x) * D_DIM + d0) =
        make_float4(a0, a1, a2, a3);
}

// ---------------- phase B: fold partials + EMA ----------------
__global__ __launch_bounds__(128)
void update_reduce_kernel(const float* __restrict__ centers,
                          const int* __restrict__ offsets,
                          const float* __restrict__ partial,
                          float* __restrict__ out_nc) {
    const int m = blockIdx.x;
    const int t = threadIdx.x;
    const int d0 = t * 4;
    const int cnt = offsets[m + 1] - offsets[m];
    float a0 = 0.0f, a1 = 0.0f, a2 = 0.0f, a3 = 0.0f;
    #pragma unroll
    for (int c = 0; c < UCHUNKS; ++c) {
        float4 v = *reinterpret_cast<const float4*>(partial + ((size_t)(m * UCHUNKS + c)) * D_DIM + d0);
        a0 += v.x; a1 += v.y; a2 += v.z; a3 += v.w;
    }
    float4 cv = *reinterpret_cast<const float4*>(centers + (size_t)m * D_DIM + d0);
    float4 r = cv;
    if (cnt > 0) {
        float inv = 1.0f / (float)cnt;
        r.x = (1.0f - TAU_F) * cv.x + TAU_F * (a0 * inv);
        r.y = (1.0f - TAU_F) * cv.y + TAU_F * (a1 * inv);
        r.z = (1.0f - TAU_F) * cv.z + TAU_F * (a2 * inv);
        r.w = (1.0f - TAU_F) * cv.w + TAU_F * (a3 * inv);
    }
    *reinterpret_cast<float4*>(out_nc + (size_t)m * D_DIM + d0) = r;
}

extern "C" void kernel_launch(void* const* d_in, const int* in_sizes, int n_in,
                              void* d_out, int out_size, void* d_ws, size_t ws_size,
                              hipStream_t stream) {
    const float* z       = (const float*)d_in[0];
    const float* centers = (const float*)d_in[1];
    const float* smean   = (const float*)d_in[2];
    const float* svar    = (const float*)d_in[3];

    float* out = (float*)d_out;
    float* out_dists = out;                                        // B*M
    float* out_idxf  = out + (size_t)B_BATCH * M_CENTERS;          // B
    float* out_masks = out_idxf + B_BATCH;                         // B*M
    float* out_nc    = out_masks + (size_t)B_BATCH * M_CENTERS;    // M*D

    char* wsp = (char*)d_ws;
    float* scale   = (float*)wsp; wsp += D_DIM * sizeof(float);
    float* shift   = (float*)wsp; wsp += D_DIM * sizeof(float);
    float* cn      = (float*)wsp; wsp += M_CENTERS * sizeof(float);
    int* ws_idx    = (int*)wsp;   wsp += (size_t)B_BATCH * sizeof(int);
    int* counts    = (int*)wsp;   wsp += M_CENTERS * sizeof(int);
    int* amb_count = (int*)wsp;   wsp += 4 * sizeof(int);          // adjacent to counts (one memset)
    int* offsets   = (int*)wsp;   wsp += (M_CENTERS + 4) * sizeof(int);
    int* cursor    = (int*)wsp;   wsp += M_CENTERS * sizeof(int);
    int* order     = (int*)wsp;   wsp += (size_t)B_BATCH * sizeof(int);
    int* amb_rows  = (int*)wsp;   wsp += (size_t)B_BATCH * sizeof(int);
    float* partial = (float*)wsp; wsp += (size_t)M_CENTERS * UCHUNKS * D_DIM * sizeof(float);
    unsigned char* cb_img = (unsigned char*)wsp; wsp += (size_t)NCHUNK * 16384;

    prep_ss_kernel<<<2, 256, 0, stream>>>(smean, svar, scale, shift);
    prep_cb_kernel<<<M_CENTERS, 64, 0, stream>>>(centers, cb_img, cn);
    hipMemsetAsync(counts, 0, (M_CENTERS + 4) * sizeof(int), stream);  // counts + amb_count
    dist_mfma_kernel<<<B_BATCH / 64, 256, 0, stream>>>(z, cb_img, scale, shift, cn,
                                                       out_dists, out_idxf, out_masks, ws_idx,
                                                       counts, amb_count, amb_rows);
    refine_kernel<<<REF_BLOCKS, 64, 0, stream>>>(z, centers, smean, svar, out_dists,
                                                 amb_count, amb_rows, out_idxf, ws_idx, counts);
    scan_kernel<<<1, 256, 0, stream>>>(counts, offsets, cursor);
    scatter2_kernel<<<B_BATCH / SC_ROWS, 256, 0, stream>>>(ws_idx, cursor, order);
    update_partial_kernel<<<M_CENTERS * UCHUNKS, 128, 0, stream>>>(z, scale, shift,
                                                                   offsets, order, partial);
    update_reduce_kernel<<<M_CENTERS, 128, 0, stream>>>(centers, offsets, partial, out_nc);
}